// Round 3
// baseline (578.991 us; speedup 1.0000x reference)
//
#include <hip/hip_runtime.h>

// GCN 2-layer. N=250000, E=4000000, 18 -> 16 -> 1.
// R5: (dst-bucket, src-window) binned edge list. Buckets shrunk to 256 dst
// nodes (977 buckets -> ~4 blocks/CU, 2x occupancy vs BN=512) and edges
// ordered by 32K-node src windows (2MB of hs1) within each bucket. All agg1
// blocks are co-resident and sweep the same window concurrently, so each
// XCD's 4MB L2 holds the live window: random gathers that previously missed
// L2 77% of the time (213MB FETCH, 9.4G miss-req/s wall) become mostly hits.
//
// out[d] = dis[d] * (sum_{s->d} hs[s] + hs[d]) + bias, hs pre-scaled by dis.

#define NB_BITS 8
#define BN (1 << NB_BITS)       // 256 dst nodes per bucket
#define NWIN_BITS 3
#define NWIN (1 << NWIN_BITS)   // 8 src windows
#define WIN_SHIFT 15            // 32768 nodes/window = 2MB of hs1
#define NBINS_PAD 8192          // >= 977 buckets * 8 windows = 7816
#define BIN_TPB 512
#define BIN_CHUNK 8192
#define AGG_TPB 512
#define ASTRIDE 17              // LDS pad: kills bank aliasing on acc
#define UF 8

// per-block LDS histogram of (dst-bucket, src-window) bins -> global bcnt
__global__ void bhist_kernel(const int* __restrict__ src, const int* __restrict__ dst,
                             int* __restrict__ bcnt, int E) {
    __shared__ int cnt[NBINS_PAD];
    int t = threadIdx.x;
    for (int i = t; i < NBINS_PAD; i += BIN_TPB) cnt[i] = 0;
    __syncthreads();
    int base = blockIdx.x * BIN_CHUNK;
    int end = min(base + BIN_CHUNK, E);
#pragma unroll 4
    for (int e = base + t; e < end; e += BIN_TPB) {
        int bin = ((dst[e] >> NB_BITS) << NWIN_BITS) | (src[e] >> WIN_SHIFT);
        atomicAdd(&cnt[bin], 1);
    }
    __syncthreads();
    for (int i = t; i < NBINS_PAD; i += BIN_TPB)
        if (cnt[i] > 0) atomicAdd(&bcnt[i], cnt[i]);
}

// exclusive scan of bcnt[NBINS_PAD] -> bstart, cursor. 1024 thr x 8 elems.
__global__ void bscan_kernel(const int* __restrict__ bcnt, int* __restrict__ bstart,
                             int* __restrict__ cursor) {
    __shared__ int s[1024];
    int t = threadIdx.x;
    int v[8];
    int sum = 0;
#pragma unroll
    for (int i = 0; i < 8; i++) {
        v[i] = bcnt[t * 8 + i];
        sum += v[i];
    }
    s[t] = sum;
    __syncthreads();
    for (int off = 1; off < 1024; off <<= 1) {
        int add = (t >= off) ? s[t - off] : 0;
        __syncthreads();
        s[t] += add;
        __syncthreads();
    }
    int excl = s[t] - sum;
#pragma unroll
    for (int i = 0; i < 8; i++) {
        bstart[t * 8 + i] = excl;
        cursor[t * 8 + i] = excl;
        excl += v[i];
    }
    if (t == 1023) bstart[NBINS_PAD] = excl;
}

// place edges: block reserves private contiguous range per bin, writes
// packed (src<<8 | dst&255) via LDS cursors. All lines single-block-owned.
__global__ void bplace_kernel(const int* __restrict__ src, const int* __restrict__ dst,
                              int* __restrict__ cursor, int* __restrict__ pairs, int E) {
    __shared__ int cnt[NBINS_PAD];  // reused as local offsets after reserve
    int t = threadIdx.x;
    for (int i = t; i < NBINS_PAD; i += BIN_TPB) cnt[i] = 0;
    __syncthreads();
    int base = blockIdx.x * BIN_CHUNK;
    int end = min(base + BIN_CHUNK, E);
#pragma unroll 4
    for (int e = base + t; e < end; e += BIN_TPB) {
        int bin = ((dst[e] >> NB_BITS) << NWIN_BITS) | (src[e] >> WIN_SHIFT);
        atomicAdd(&cnt[bin], 1);
    }
    __syncthreads();
    for (int i = t; i < NBINS_PAD; i += BIN_TPB) {
        int c = cnt[i];
        cnt[i] = (c > 0) ? atomicAdd(&cursor[i], c) : 0;  // same-index overwrite, no hazard
    }
    __syncthreads();
#pragma unroll 4
    for (int e = base + t; e < end; e += BIN_TPB) {
        int d = dst[e];
        int sv = src[e];
        int bin = ((d >> NB_BITS) << NWIN_BITS) | (sv >> WIN_SHIFT);
        int p = atomicAdd(&cnt[bin], 1);
        pairs[p] = (sv << NB_BITS) | (d & (BN - 1));
    }
}

// per-bucket in-degree via LDS counters -> dis = rsqrt(deg+1)
__global__ void degdis_kernel(const int* __restrict__ pairs, const int* __restrict__ bstart,
                              float* __restrict__ dis, int N) {
    __shared__ int cnt[BN];
    int b = blockIdx.x, t = threadIdx.x;
    for (int i = t; i < BN; i += blockDim.x) cnt[i] = 0;
    __syncthreads();
    int s0 = bstart[b << NWIN_BITS], s1 = bstart[(b + 1) << NWIN_BITS];
#pragma unroll 4
    for (int e = s0 + t; e < s1; e += blockDim.x)
        atomicAdd(&cnt[pairs[e] & (BN - 1)], 1);
    __syncthreads();
    int nbase = b << NB_BITS;
    for (int i = t; i < BN; i += blockDim.x) {
        int n = nbase + i;
        if (n < N) dis[n] = rsqrtf((float)cnt[i] + 1.0f);
    }
}

// hs1[n,f] = (x[n] @ W1)[f] * dis[n]
__global__ void h1_kernel(const float* __restrict__ x, const float* __restrict__ W1,
                          const float* __restrict__ dis, float* __restrict__ hs1, int N) {
    __shared__ float w[18 * 16];
    for (int i = threadIdx.x; i < 18 * 16; i += blockDim.x) w[i] = W1[i];
    __syncthreads();
    int n = blockIdx.x * blockDim.x + threadIdx.x;
    if (n >= N) return;
    const float2* x2 = (const float2*)(x + (size_t)n * 18);
    float xv[18];
#pragma unroll
    for (int k = 0; k < 9; k++) {
        float2 v = x2[k];
        xv[2 * k] = v.x;
        xv[2 * k + 1] = v.y;
    }
    float d = dis[n];
    float acc[16];
#pragma unroll
    for (int f = 0; f < 16; f++) acc[f] = 0.0f;
#pragma unroll
    for (int k = 0; k < 18; k++) {
        float xk = xv[k];
#pragma unroll
        for (int f = 0; f < 16; f++) acc[f] = fmaf(xk, w[k * 16 + f], acc[f]);
    }
    float4* outp = (float4*)(hs1 + (size_t)n * 16);
#pragma unroll
    for (int q = 0; q < 4; q++) {
        float4 v;
        v.x = acc[q * 4 + 0] * d;
        v.y = acc[q * 4 + 1] * d;
        v.z = acc[q * 4 + 2] * d;
        v.w = acc[q * 4 + 3] * d;
        outp[q] = v;
    }
}

// layer-1: per-bucket LDS accumulate (16 lanes/edge), 8x-unrolled gather.
// edges arrive src-window-ordered -> gathers stay in the L2-resident window.
// epilogue: relu + W2 dot + dis scale -> hs2
__global__ void agg1_kernel(const int* __restrict__ pairs, const int* __restrict__ bstart,
                            const float* __restrict__ hs1, const float* __restrict__ dis,
                            const float* __restrict__ b1, const float* __restrict__ W2,
                            float* __restrict__ hs2, int N) {
    __shared__ float acc[BN * ASTRIDE];  // ~17.4 KB -> 4 blocks/CU
    int b = blockIdx.x, t = threadIdx.x;
    for (int i = t; i < BN * ASTRIDE; i += AGG_TPB) acc[i] = 0.f;
    __syncthreads();
    int s0 = bstart[b << NWIN_BITS], s1 = bstart[(b + 1) << NWIN_BITS];
    int f = t & 15;
    const int G = AGG_TPB / 16;  // 32 edge-groups
    int e = s0 + (t >> 4);
    // main: 8 independent pairs loads -> 8 independent gathers -> 8 LDS atomics
    for (; e + (UF - 1) * G < s1; e += UF * G) {
        int pv[UF];
        float v[UF];
#pragma unroll
        for (int u = 0; u < UF; u++) pv[u] = pairs[e + u * G];
#pragma unroll
        for (int u = 0; u < UF; u++) v[u] = hs1[(size_t)(pv[u] >> NB_BITS) * 16 + f];
#pragma unroll
        for (int u = 0; u < UF; u++) atomicAdd(&acc[(pv[u] & (BN - 1)) * ASTRIDE + f], v[u]);
    }
    for (; e < s1; e += G) {
        int pv = pairs[e];
        atomicAdd(&acc[(pv & (BN - 1)) * ASTRIDE + f], hs1[(size_t)(pv >> NB_BITS) * 16 + f]);
    }
    __syncthreads();
    int nbase = b << NB_BITS;
    float bbf = b1[f], wwf = W2[f];
    for (int nl = t >> 4; nl < BN; nl += G) {
        int n = nbase + nl;
        float d = 0.f, p = 0.f;
        if (n < N) {
            d = dis[n];
            float self = hs1[(size_t)n * 16 + f];
            p = fmaxf(d * (acc[nl * ASTRIDE + f] + self) + bbf, 0.f) * wwf;
        }
        p += __shfl_xor(p, 1);
        p += __shfl_xor(p, 2);
        p += __shfl_xor(p, 4);
        p += __shfl_xor(p, 8);
        if (f == 0 && n < N) hs2[n] = p * d;
    }
}

// layer-2: per-bucket LDS accumulate of hs2, 8x-unrolled, epilogue self+bias
__global__ void agg2_kernel(const int* __restrict__ pairs, const int* __restrict__ bstart,
                            const float* __restrict__ hs2, const float* __restrict__ dis,
                            const float* __restrict__ b2, float* __restrict__ out, int N) {
    __shared__ float acc[BN];
    int b = blockIdx.x, t = threadIdx.x;
    for (int i = t; i < BN; i += AGG_TPB) acc[i] = 0.f;
    __syncthreads();
    int s0 = bstart[b << NWIN_BITS], s1 = bstart[(b + 1) << NWIN_BITS];
    int e = s0 + t;
    for (; e + (UF - 1) * AGG_TPB < s1; e += UF * AGG_TPB) {
        int pv[UF];
        float v[UF];
#pragma unroll
        for (int u = 0; u < UF; u++) pv[u] = pairs[e + u * AGG_TPB];
#pragma unroll
        for (int u = 0; u < UF; u++) v[u] = hs2[pv[u] >> NB_BITS];
#pragma unroll
        for (int u = 0; u < UF; u++) atomicAdd(&acc[pv[u] & (BN - 1)], v[u]);
    }
    for (; e < s1; e += AGG_TPB) {
        int pv = pairs[e];
        atomicAdd(&acc[pv & (BN - 1)], hs2[pv >> NB_BITS]);
    }
    __syncthreads();
    int nbase = b << NB_BITS;
    for (int i = t; i < BN; i += AGG_TPB) {
        int n = nbase + i;
        if (n < N) out[n] = dis[n] * (acc[i] + hs2[n]) + b2[0];
    }
}

extern "C" void kernel_launch(void* const* d_in, const int* in_sizes, int n_in,
                              void* d_out, int out_size, void* d_ws, size_t ws_size,
                              hipStream_t stream) {
    const float* x = (const float*)d_in[0];
    const int* edge_index = (const int*)d_in[1];
    const float* W1 = (const float*)d_in[2];
    const float* b1 = (const float*)d_in[3];
    const float* W2 = (const float*)d_in[4];
    const float* b2 = (const float*)d_in[5];
    float* out = (float*)d_out;

    const int N = in_sizes[0] / 18;
    const int E = in_sizes[1] / 2;
    const int* src = edge_index;
    const int* dst = edge_index + E;
    const int NBUCKET = (N + BN - 1) / BN;  // 977

    // ws layout (4B words): pairs[E], hs1[16N], hs2[N], dis[N],
    // bstart[NBINS_PAD+1], cursor[NBINS_PAD], bcnt[NBINS_PAD]  ~= 34.1 MB
    int* ws = (int*)d_ws;
    int* pairs = ws;
    float* hs1 = (float*)(ws + (size_t)E);
    float* hs2 = hs1 + (size_t)16 * N;
    float* dis = hs2 + N;
    int* bstart = (int*)(dis + N);
    int* cursor = bstart + NBINS_PAD + 1;
    int* bcnt = cursor + NBINS_PAD;

    hipMemsetAsync(bcnt, 0, NBINS_PAD * sizeof(int), stream);

    int binBlocks = (E + BIN_CHUNK - 1) / BIN_CHUNK;  // 489
    int nBlocksN = (N + 255) / 256;

    bhist_kernel<<<binBlocks, BIN_TPB, 0, stream>>>(src, dst, bcnt, E);
    bscan_kernel<<<1, 1024, 0, stream>>>(bcnt, bstart, cursor);
    bplace_kernel<<<binBlocks, BIN_TPB, 0, stream>>>(src, dst, cursor, pairs, E);
    degdis_kernel<<<NBUCKET, 512, 0, stream>>>(pairs, bstart, dis, N);
    h1_kernel<<<nBlocksN, 256, 0, stream>>>(x, W1, dis, hs1, N);
    agg1_kernel<<<NBUCKET, AGG_TPB, 0, stream>>>(pairs, bstart, hs1, dis, b1, W2, hs2, N);
    agg2_kernel<<<NBUCKET, AGG_TPB, 0, stream>>>(pairs, bstart, hs2, dis, b2, out, N);
}

// Round 6
// 552.560 us; speedup vs baseline: 1.0478x; 1.0478x over previous
//
#include <hip/hip_runtime.h>
#include <hip/hip_fp16.h>

// GCN 2-layer. N=250000, E=4000000, 18 -> 16 -> 1.
// R7: fp16 hs1. R4/R5 established agg1 dur == FETCH/610GB/s (random-gather
// wall; VALU 3.8%, occupancy-insensitive). R6's grid.sync cohort broke under
// graph capture -> reverted; window binning bought nothing -> dropped.
// Lever: hs1 rows 64B fp32 -> 32B fp16. Halves logical gather volume
// (256->128MB) AND halves the working set (16->8MB vs 4MB/XCD L2), so both
// byte-bound and miss-request-bound interpretations of the wall improve.
// LDS accumulation stays fp32; hs2/layer-2 stay fp32. Added rounding error
// ~3-5e-4, threshold 4.6e-3.
//
// out[d] = dis[d] * (sum_{s->d} hs[s] + hs[d]) + bias, hs pre-scaled by dis.

#define NB_BITS 8
#define BN (1 << NB_BITS)       // 256 dst nodes per bucket
#define NBINS 1024              // >= 977 buckets
#define BIN_TPB 512
#define BIN_CHUNK 8192
#define AGG_TPB 512
#define ASTRIDE 17              // LDS pad: kills bank aliasing on acc
#define UF 8

// per-block LDS histogram of dst buckets -> global bcnt
__global__ void bhist_kernel(const int* __restrict__ dst, int* __restrict__ bcnt, int E) {
    __shared__ int cnt[NBINS];
    int t = threadIdx.x;
    for (int i = t; i < NBINS; i += BIN_TPB) cnt[i] = 0;
    __syncthreads();
    int base = blockIdx.x * BIN_CHUNK;
    int end = min(base + BIN_CHUNK, E);
#pragma unroll 4
    for (int e = base + t; e < end; e += BIN_TPB)
        atomicAdd(&cnt[dst[e] >> NB_BITS], 1);
    __syncthreads();
    for (int i = t; i < NBINS; i += BIN_TPB)
        if (cnt[i] > 0) atomicAdd(&bcnt[i], cnt[i]);
}

// exclusive scan of bcnt[NBINS] -> bstart, cursor
__global__ void bscan_kernel(const int* __restrict__ bcnt, int* __restrict__ bstart,
                             int* __restrict__ cursor) {
    __shared__ int s[NBINS];
    int t = threadIdx.x;  // NBINS threads
    int v = bcnt[t];
    s[t] = v;
    __syncthreads();
    for (int off = 1; off < NBINS; off <<= 1) {
        int add = (t >= off) ? s[t - off] : 0;
        __syncthreads();
        s[t] += add;
        __syncthreads();
    }
    int excl = s[t] - v;
    bstart[t] = excl;
    cursor[t] = excl;
    if (t == NBINS - 1) bstart[NBINS] = s[t];
}

// place edges: block reserves private contiguous range per bucket, writes
// packed (src<<8 | dst&255) via LDS cursors. All lines single-block-owned.
__global__ void bplace_kernel(const int* __restrict__ src, const int* __restrict__ dst,
                              int* __restrict__ cursor, int* __restrict__ pairs, int E) {
    __shared__ int cnt[NBINS];  // reused as local offsets after reserve
    int t = threadIdx.x;
    for (int i = t; i < NBINS; i += BIN_TPB) cnt[i] = 0;
    __syncthreads();
    int base = blockIdx.x * BIN_CHUNK;
    int end = min(base + BIN_CHUNK, E);
#pragma unroll 4
    for (int e = base + t; e < end; e += BIN_TPB)
        atomicAdd(&cnt[dst[e] >> NB_BITS], 1);
    __syncthreads();
    for (int i = t; i < NBINS; i += BIN_TPB) {
        int c = cnt[i];
        cnt[i] = (c > 0) ? atomicAdd(&cursor[i], c) : 0;  // same-index overwrite, no hazard
    }
    __syncthreads();
#pragma unroll 4
    for (int e = base + t; e < end; e += BIN_TPB) {
        int d = dst[e];
        int sv = src[e];
        int b = d >> NB_BITS;
        int p = atomicAdd(&cnt[b], 1);
        pairs[p] = (sv << NB_BITS) | (d & (BN - 1));
    }
}

// per-bucket in-degree via LDS counters -> dis = rsqrt(deg+1)
__global__ void degdis_kernel(const int* __restrict__ pairs, const int* __restrict__ bstart,
                              float* __restrict__ dis, int N) {
    __shared__ int cnt[BN];
    int b = blockIdx.x, t = threadIdx.x;
    for (int i = t; i < BN; i += blockDim.x) cnt[i] = 0;
    __syncthreads();
    int s0 = bstart[b], s1 = bstart[b + 1];
#pragma unroll 4
    for (int e = s0 + t; e < s1; e += blockDim.x)
        atomicAdd(&cnt[pairs[e] & (BN - 1)], 1);
    __syncthreads();
    int nbase = b << NB_BITS;
    for (int i = t; i < BN; i += blockDim.x) {
        int n = nbase + i;
        if (n < N) dis[n] = rsqrtf((float)cnt[i] + 1.0f);
    }
}

// hs1h[n,f] = fp16( (x[n] @ W1)[f] * dis[n] )   -- 32B/row
__global__ void h1_kernel(const float* __restrict__ x, const float* __restrict__ W1,
                          const float* __restrict__ dis, __half* __restrict__ hs1h, int N) {
    __shared__ float w[18 * 16];
    for (int i = threadIdx.x; i < 18 * 16; i += blockDim.x) w[i] = W1[i];
    __syncthreads();
    int n = blockIdx.x * blockDim.x + threadIdx.x;
    if (n >= N) return;
    const float2* x2 = (const float2*)(x + (size_t)n * 18);
    float xv[18];
#pragma unroll
    for (int k = 0; k < 9; k++) {
        float2 v = x2[k];
        xv[2 * k] = v.x;
        xv[2 * k + 1] = v.y;
    }
    float d = dis[n];
    float acc[16];
#pragma unroll
    for (int f = 0; f < 16; f++) acc[f] = 0.0f;
#pragma unroll
    for (int k = 0; k < 18; k++) {
        float xk = xv[k];
#pragma unroll
        for (int f = 0; f < 16; f++) acc[f] = fmaf(xk, w[k * 16 + f], acc[f]);
    }
    unsigned int u[8];
#pragma unroll
    for (int q = 0; q < 8; q++) {
        unsigned int lo = __half_as_ushort(__float2half_rn(acc[2 * q] * d));
        unsigned int hi = __half_as_ushort(__float2half_rn(acc[2 * q + 1] * d));
        u[q] = lo | (hi << 16);
    }
    uint4* outp = (uint4*)(hs1h + (size_t)n * 16);
    outp[0] = make_uint4(u[0], u[1], u[2], u[3]);
    outp[1] = make_uint4(u[4], u[5], u[6], u[7]);
}

// layer-1: per-bucket LDS accumulate (16 lanes/edge), 8x-unrolled fp16 gather.
// epilogue: relu + W2 dot + dis scale -> hs2 (fp32)
__global__ void agg1_kernel(const int* __restrict__ pairs, const int* __restrict__ bstart,
                            const __half* __restrict__ hs1h, const float* __restrict__ dis,
                            const float* __restrict__ b1, const float* __restrict__ W2,
                            float* __restrict__ hs2, int N) {
    __shared__ float acc[BN * ASTRIDE];  // ~17.4 KB -> 4 blocks/CU
    int b = blockIdx.x, t = threadIdx.x;
    for (int i = t; i < BN * ASTRIDE; i += AGG_TPB) acc[i] = 0.f;
    __syncthreads();
    int s0 = bstart[b], s1 = bstart[b + 1];
    int f = t & 15;
    const int G = AGG_TPB / 16;  // 32 edge-groups
    int e = s0 + (t >> 4);
    // main: 8 independent pairs loads -> 8 independent 2B gathers -> 8 LDS atomics
    for (; e + (UF - 1) * G < s1; e += UF * G) {
        int pv[UF];
        float v[UF];
#pragma unroll
        for (int u = 0; u < UF; u++) pv[u] = pairs[e + u * G];
#pragma unroll
        for (int u = 0; u < UF; u++)
            v[u] = __half2float(hs1h[(size_t)(pv[u] >> NB_BITS) * 16 + f]);
#pragma unroll
        for (int u = 0; u < UF; u++) atomicAdd(&acc[(pv[u] & (BN - 1)) * ASTRIDE + f], v[u]);
    }
    for (; e < s1; e += G) {
        int pv = pairs[e];
        atomicAdd(&acc[(pv & (BN - 1)) * ASTRIDE + f],
                  __half2float(hs1h[(size_t)(pv >> NB_BITS) * 16 + f]));
    }
    __syncthreads();
    int nbase = b << NB_BITS;
    float bbf = b1[f], wwf = W2[f];
    for (int nl = t >> 4; nl < BN; nl += G) {
        int n = nbase + nl;
        float d = 0.f, p = 0.f;
        if (n < N) {
            d = dis[n];
            float self = __half2float(hs1h[(size_t)n * 16 + f]);
            p = fmaxf(d * (acc[nl * ASTRIDE + f] + self) + bbf, 0.f) * wwf;
        }
        p += __shfl_xor(p, 1);
        p += __shfl_xor(p, 2);
        p += __shfl_xor(p, 4);
        p += __shfl_xor(p, 8);
        if (f == 0 && n < N) hs2[n] = p * d;
    }
}

// layer-2: per-bucket LDS accumulate of hs2, 8x-unrolled, epilogue self+bias
__global__ void agg2_kernel(const int* __restrict__ pairs, const int* __restrict__ bstart,
                            const float* __restrict__ hs2, const float* __restrict__ dis,
                            const float* __restrict__ b2, float* __restrict__ out, int N) {
    __shared__ float acc[BN];
    int b = blockIdx.x, t = threadIdx.x;
    for (int i = t; i < BN; i += AGG_TPB) acc[i] = 0.f;
    __syncthreads();
    int s0 = bstart[b], s1 = bstart[b + 1];
    int e = s0 + t;
    for (; e + (UF - 1) * AGG_TPB < s1; e += UF * AGG_TPB) {
        int pv[UF];
        float v[UF];
#pragma unroll
        for (int u = 0; u < UF; u++) pv[u] = pairs[e + u * AGG_TPB];
#pragma unroll
        for (int u = 0; u < UF; u++) v[u] = hs2[pv[u] >> NB_BITS];
#pragma unroll
        for (int u = 0; u < UF; u++) atomicAdd(&acc[pv[u] & (BN - 1)], v[u]);
    }
    for (; e < s1; e += AGG_TPB) {
        int pv = pairs[e];
        atomicAdd(&acc[pv & (BN - 1)], hs2[pv >> NB_BITS]);
    }
    __syncthreads();
    int nbase = b << NB_BITS;
    for (int i = t; i < BN; i += AGG_TPB) {
        int n = nbase + i;
        if (n < N) out[n] = dis[n] * (acc[i] + hs2[n]) + b2[0];
    }
}

extern "C" void kernel_launch(void* const* d_in, const int* in_sizes, int n_in,
                              void* d_out, int out_size, void* d_ws, size_t ws_size,
                              hipStream_t stream) {
    const float* x = (const float*)d_in[0];
    const int* edge_index = (const int*)d_in[1];
    const float* W1 = (const float*)d_in[2];
    const float* b1 = (const float*)d_in[3];
    const float* W2 = (const float*)d_in[4];
    const float* b2 = (const float*)d_in[5];
    float* out = (float*)d_out;

    const int N = in_sizes[0] / 18;
    const int E = in_sizes[1] / 2;
    const int* src = edge_index;
    const int* dst = edge_index + E;
    const int NBUCKET = (N + BN - 1) / BN;  // 977

    // ws layout (4B words): pairs[E], hs1h[16N halves = 8N words], hs2[N],
    // dis[N], bstart[NBINS+1], cursor[NBINS], bcnt[NBINS]  ~= 26 MB
    int* ws = (int*)d_ws;
    int* pairs = ws;
    __half* hs1h = (__half*)(ws + (size_t)E);           // 16MB-aligned base
    float* hs2 = (float*)(ws + (size_t)E + 8 * (size_t)N);
    float* dis = hs2 + N;
    int* bstart = (int*)(dis + N);
    int* cursor = bstart + NBINS + 1;
    int* bcnt = cursor + NBINS;

    hipMemsetAsync(bcnt, 0, NBINS * sizeof(int), stream);

    int binBlocks = (E + BIN_CHUNK - 1) / BIN_CHUNK;  // 489
    int nBlocksN = (N + 255) / 256;

    bhist_kernel<<<binBlocks, BIN_TPB, 0, stream>>>(dst, bcnt, E);
    bscan_kernel<<<1, NBINS, 0, stream>>>(bcnt, bstart, cursor);
    bplace_kernel<<<binBlocks, BIN_TPB, 0, stream>>>(src, dst, cursor, pairs, E);
    degdis_kernel<<<NBUCKET, 512, 0, stream>>>(pairs, bstart, dis, N);
    h1_kernel<<<nBlocksN, 256, 0, stream>>>(x, W1, dis, hs1h, N);
    agg1_kernel<<<NBUCKET, AGG_TPB, 0, stream>>>(pairs, bstart, hs1h, dis, b1, W2, hs2, N);
    agg2_kernel<<<NBUCKET, AGG_TPB, 0, stream>>>(pairs, bstart, hs2, dis, b2, out, N);
}